// Round 5
// baseline (544.512 us; speedup 1.0000x reference)
//
#include <hip/hip_runtime.h>

typedef __bf16 bf16_t;
typedef __bf16 bf16x8 __attribute__((ext_vector_type(8)));
typedef float f32x4 __attribute__((ext_vector_type(4)));

#define INF 256
#define HF 128
#define NPB 16
#define CH 8
#define NSL 128
#define PCH 8
#define SCAN_STRIDE 512

// ---- roots[g] = first node of graph g (batch sorted, all graphs non-empty) ----
__global__ void k_roots(const int* __restrict__ batch, int* __restrict__ roots, int N, int B) {
    int i = blockIdx.x * blockDim.x + threadIdx.x;
    if (i == 0) roots[B] = N;
    if (i < N) {
        if (i == 0) roots[batch[0]] = 0;
        else if (batch[i] != batch[i - 1]) roots[batch[i]] = i;
    }
}

__global__ void k_zero(int* __restrict__ p, int n) {
    int i = blockIdx.x * blockDim.x + threadIdx.x;
    if (i < n) p[i] = 0;
}

// two W1 matrices (256x128 f32) -> bf16 MFMA B-fragment order, 32768 each
__global__ void k_wswz2(const float* __restrict__ tw1, const float* __restrict__ bw1,
                        bf16_t* __restrict__ o) {
    int idx = blockIdx.x * blockDim.x + threadIdx.x;
    if (idx >= 65536) return;
    const float* W = (idx < 32768) ? tw1 : bw1;
    bf16_t* out = o + (idx & 32768);
    int i = idx & 32767;
    int j  = i & 7;
    int l  = (i >> 3) & 63;
    int t  = i >> 9;          // kk*8 + n
    int n  = t & 7;
    int kk = t >> 3;
    int k  = kk * 32 + ((l >> 4) << 3) + j;
    int c  = (n << 4) + (l & 15);
    out[i] = (bf16_t)W[k * HF + c];
}

// in-degree for both directions. TD: d=dst. BU: d=src. Virtual edge N->root.
__global__ void k_degboth(const int* __restrict__ src, const int* __restrict__ dst,
                          const int* __restrict__ roots, int* __restrict__ indeg,
                          int E, int B, int N, int nv) {
    int e = blockIdx.x * blockDim.x + threadIdx.x;
    if (e >= E + B) return;
    int a, b;
    if (e < E) { a = src[e]; b = dst[e]; }
    else       { a = N;      b = roots[e - E]; }
    atomicAdd(&indeg[b], 1);        // TD
    atomicAdd(&indeg[nv + a], 1);   // BU
}

__global__ void k_dinvboth(const int* __restrict__ indeg, float* __restrict__ dinv, int n2) {
    int i = blockIdx.x * blockDim.x + threadIdx.x;
    if (i < n2) dinv[i] = rsqrtf(1.0f + (float)indeg[i]);  // +1 self-loop
}

// pb[dir][v] = {batch[v], bits(dinv[dir][v])}
__global__ void k_packpb(const int* __restrict__ batch, const float* __restrict__ dinv,
                         int2* __restrict__ pb, int nv, int N) {
    int i = blockIdx.x * blockDim.x + threadIdx.x;
    if (i >= 2 * nv) return;
    int v = (i >= nv) ? (i - nv) : i;
    int g = (v < N) ? batch[v] : 0;
    pb[i] = make_int2(g, __float_as_int(dinv[i]));
}

// per-256-chunk sums
__global__ __launch_bounds__(256) void k_scan1(const int* __restrict__ indeg, int* __restrict__ bsum, int nv) {
    int dir = blockIdx.y;
    __shared__ int s[256];
    int t = threadIdx.x;
    int v = blockIdx.x * 256 + t;
    s[t] = (v < nv) ? indeg[dir * nv + v] : 0;
    __syncthreads();
    for (int off = 128; off > 0; off >>= 1) {
        if (t < off) s[t] += s[t + off];
        __syncthreads();
    }
    if (t == 0) bsum[dir * SCAN_STRIDE + blockIdx.x] = s[0];
}

// exclusive scan of block sums (nblk <= 512)
__global__ __launch_bounds__(512) void k_scan2(int* __restrict__ bsum, int nblk) {
    int dir = blockIdx.y;
    int* p = bsum + dir * SCAN_STRIDE;
    __shared__ int s[512];
    int t = threadIdx.x;
    int v = (t < nblk) ? p[t] : 0;
    s[t] = v;
    __syncthreads();
    for (int off = 1; off < 512; off <<= 1) {
        int u = (t >= off) ? s[t - off] : 0;
        __syncthreads();
        s[t] += u;
        __syncthreads();
    }
    if (t < nblk) p[t] = s[t] - v;  // exclusive
}

// per-element exclusive offsets + cursor copy
__global__ __launch_bounds__(256) void k_scan3(const int* __restrict__ indeg, const int* __restrict__ bsum,
                                               int* __restrict__ off, int* __restrict__ cursor,
                                               int nv, int total) {
    int dir = blockIdx.y;
    __shared__ int s[256];
    int t = threadIdx.x;
    int v0 = blockIdx.x * 256 + t;
    int val = (v0 < nv) ? indeg[dir * nv + v0] : 0;
    s[t] = val;
    __syncthreads();
    for (int o = 1; o < 256; o <<= 1) {
        int u = (t >= o) ? s[t - o] : 0;
        __syncthreads();
        s[t] += u;
        __syncthreads();
    }
    int excl = s[t] - val + bsum[dir * SCAN_STRIDE + blockIdx.x];
    if (v0 < nv) {
        off[dir * (nv + 1) + v0] = excl;
        cursor[dir * nv + v0] = excl;
    }
    if (blockIdx.x == 0 && t == 0) off[dir * (nv + 1) + nv] = total;
}

// fill slot + owner lists for both directions
__global__ void k_fill(const int* __restrict__ src, const int* __restrict__ dst,
                       const int* __restrict__ roots, int* __restrict__ cursor,
                       int* __restrict__ slots, int* __restrict__ dsts,
                       int E, int B, int N, int nv) {
    int e = blockIdx.x * blockDim.x + threadIdx.x;
    if (e >= E + B) return;
    int EB = E + B;
    int a, b;
    if (e < E) { a = src[e]; b = dst[e]; }
    else       { a = N;      b = roots[e - E]; }
    int p = atomicAdd(&cursor[b], 1);            // TD: owner b, source a
    slots[p] = a; dsts[p] = b;
    p = atomicAdd(&cursor[nv + a], 1);           // BU: owner a, source b
    slots[EB + p] = b; dsts[EB + p] = a;
}

// Dual-direction MFMA GEMM1 reading f32 X directly:
//   rawsTD[r] = dinvTD[r]*(X W1td)[r], rawsBU[r] = dinvBU[r]*(X W1bu)[r]  (bf16)
__global__ __launch_bounds__(256) void k_gemm1both(
    const float* __restrict__ x, const float* __restrict__ emb,
    const bf16_t* __restrict__ WfTD, const bf16_t* __restrict__ WfBU,
    const float* __restrict__ dinvTD, const float* __restrict__ dinvBU,
    bf16_t* __restrict__ rawsTD, bf16_t* __restrict__ rawsBU,
    int nv, int N)
{
    int lane = threadIdx.x & 63;
    int wave = threadIdx.x >> 6;
    int rowbase = blockIdx.x * 64 + wave * 16;
    int r = rowbase + (lane & 15);
    int kseg = lane >> 4;
    const float* xr = (r < N) ? (x + (size_t)r * INF) : emb;

    bf16x8 a[8];
    #pragma unroll
    for (int h = 0; h < 2; ++h) {
        float4 f[8];
        #pragma unroll
        for (int kk = 0; kk < 4; ++kk) {
            int k0 = (h * 4 + kk) * 32 + kseg * 8;
            f[2 * kk]     = *reinterpret_cast<const float4*>(xr + k0);
            f[2 * kk + 1] = *reinterpret_cast<const float4*>(xr + k0 + 4);
        }
        #pragma unroll
        for (int kk = 0; kk < 4; ++kk) {
            bf16x8 av;
            av[0] = (__bf16)f[2 * kk].x;     av[1] = (__bf16)f[2 * kk].y;
            av[2] = (__bf16)f[2 * kk].z;     av[3] = (__bf16)f[2 * kk].w;
            av[4] = (__bf16)f[2 * kk + 1].x; av[5] = (__bf16)f[2 * kk + 1].y;
            av[6] = (__bf16)f[2 * kk + 1].z; av[7] = (__bf16)f[2 * kk + 1].w;
            a[h * 4 + kk] = av;
        }
    }

    f32x4 accT[8] = {}, accB[8] = {};
    #pragma unroll
    for (int kk = 0; kk < 8; ++kk) {
        #pragma unroll
        for (int n = 0; n < 8; ++n) {
            size_t wi = (size_t)((((kk << 3) + n) << 6) + lane) * 8;
            bf16x8 bt = *reinterpret_cast<const bf16x8*>(WfTD + wi);
            accT[n] = __builtin_amdgcn_mfma_f32_16x16x32_bf16(a[kk], bt, accT[n], 0, 0, 0);
            bf16x8 bb = *reinterpret_cast<const bf16x8*>(WfBU + wi);
            accB[n] = __builtin_amdgcn_mfma_f32_16x16x32_bf16(a[kk], bb, accB[n], 0, 0, 0);
        }
    }

    int ccol = lane & 15;
    int cg = lane >> 4;
    #pragma unroll
    for (int i = 0; i < 4; ++i) {
        int rr = rowbase + cg * 4 + i;
        if (rr >= nv) continue;
        float diT = dinvTD[rr], diB = dinvBU[rr];
        bf16_t* oT = rawsTD + (size_t)rr * HF + ccol;
        bf16_t* oB = rawsBU + (size_t)rr * HF + ccol;
        #pragma unroll
        for (int n = 0; n < 8; ++n) {
            oT[n * 16] = (bf16_t)(accT[n][i] * diT);
            oB[n * 16] = (bf16_t)(accB[n][i] * diB);
        }
    }
}

// layer-1 gather, both dirs: ab[v] = relu(dinv[v]*(raws[v] + sum_in raws[s]) + b1)
// owner per slot comes from dsts -> no bucket search, no __syncthreads (column-private)
__global__ __launch_bounds__(128) void k_gather1(
    const bf16_t* __restrict__ raws, const int* __restrict__ off,
    const int* __restrict__ slots, const int* __restrict__ dsts,
    const float* __restrict__ dinv,
    const float* __restrict__ td_b1, const float* __restrict__ bu_b1,
    bf16_t* __restrict__ ab, int nv, int EB)
{
    int dir = blockIdx.y;
    const bf16_t* R  = raws + (size_t)dir * nv * HF;
    const int*    OF = off + (size_t)dir * (nv + 1);
    const int*    SL = slots + (size_t)dir * EB;
    const int*    DS = dsts + (size_t)dir * EB;
    const float*  DV = dinv + (size_t)dir * nv;
    const float*  bias = dir ? bu_b1 : td_b1;
    bf16_t* AB = ab + (size_t)dir * nv * HF;

    __shared__ float lsum[NPB][HF];
    int t = threadIdx.x;
    int v0 = blockIdx.x * NPB;
    int nloc = min(NPB, nv - v0);

    #pragma unroll 1
    for (int j = 0; j < nloc; ++j)
        lsum[j][t] = (float)R[(size_t)(v0 + j) * HF + t];

    int e0 = OF[v0], e1 = OF[v0 + nloc];
    #pragma unroll 1
    for (int i = e0; i < e1; i += CH) {
        int cnt = min(CH, e1 - i);
        int sl[CH], dd[CH]; float vals[CH];
        #pragma unroll
        for (int u = 0; u < CH; ++u) if (u < cnt) { sl[u] = SL[i + u]; dd[u] = DS[i + u]; }
        #pragma unroll
        for (int u = 0; u < CH; ++u) if (u < cnt) vals[u] = (float)R[(size_t)sl[u] * HF + t];
        #pragma unroll
        for (int u = 0; u < CH; ++u) if (u < cnt) lsum[dd[u] - v0][t] += vals[u];
    }

    float bs = bias[t];
    #pragma unroll 1
    for (int j = 0; j < nloc; ++j) {
        int v = v0 + j;
        float val = DV[v] * lsum[j][t] + bs;
        AB[(size_t)v * HF + t] = (bf16_t)fmaxf(val, 0.f);
    }
}

// Layer-2 scatter-pool: pooled[g] = sum_v in g of (A_hat H)[v], computed source-major.
// Node s contributes dv[s]^2*H[s] to graph batch[s], and dv[s]*dv[v]*H[s] to batch[v]
// for each out-neighbor v (out-CSR of dir D == in-CSR of dir 1-D).
// Per-slice accumulation in a 64KB LDS [128][128] tile, flushed to partial[slice].
__global__ __launch_bounds__(256) void k_pool2(
    const bf16_t* __restrict__ ab, const int* __restrict__ off,
    const int* __restrict__ slots, const int* __restrict__ dsts,
    const float* __restrict__ dinv, const int* __restrict__ batch,
    const int2* __restrict__ pb, float* __restrict__ partial,
    float* __restrict__ vrow, int nv, int EB, int N)
{
    int D = blockIdx.y;
    int slice = blockIdx.x;
    const bf16_t* H = ab + (size_t)D * nv * HF;
    const float* DV = dinv + (size_t)D * nv;
    int O = 1 - D;
    const int* oOF = off + (size_t)O * (nv + 1);
    const int* oSL = slots + (size_t)O * EB;
    const int* oDS = dsts + (size_t)O * EB;
    const int2* PB = pb + (size_t)D * nv;
    float* VR = vrow + D * HF;

    __shared__ float lsum[128][HF];
    int t = threadIdx.x;
    int col = t & 127;
    int sub = t >> 7;

    for (int g = sub; g < 128; g += 2) lsum[g][col] = 0.f;
    __syncthreads();

    int chunkN = (nv + NSL - 1) / NSL;
    int lo = min(slice * chunkN, nv);
    int hi = min(lo + chunkN, nv);
    float dvN = DV[N];

    // self terms (batch sorted -> run-length accumulate, 1-2 LDS atomics per run)
    int curg = -1; float accum = 0.f;
    #pragma unroll 1
    for (int v = lo + sub; v < hi; v += 2) {
        float h = (float)H[(size_t)v * HF + col];
        float dv = DV[v];
        float w = dv * dv * h;
        if (v == N) { atomicAdd(&VR[col], w); continue; }
        int g = batch[v];
        if (g != curg) {
            if (curg >= 0) atomicAdd(&lsum[curg][col], accum);
            curg = g; accum = 0.f;
        }
        accum += w;
    }
    if (curg >= 0) atomicAdd(&lsum[curg][col], accum);

    // edge terms: sequential owner stream, random 8B pb lookups, PCH-deep ILP
    int e0 = oOF[lo], e1 = oOF[hi];
    #pragma unroll 1
    for (int i = e0 + sub * PCH; i < e1; i += 2 * PCH) {
        int cnt = min(PCH, e1 - i);
        int sv[PCH], tv[PCH];
        #pragma unroll
        for (int u = 0; u < PCH; ++u) if (u < cnt) { sv[u] = oDS[i + u]; tv[u] = oSL[i + u]; }
        int2 pv[PCH]; float hh[PCH], ds[PCH];
        #pragma unroll
        for (int u = 0; u < PCH; ++u) if (u < cnt) pv[u] = PB[tv[u]];
        #pragma unroll
        for (int u = 0; u < PCH; ++u) if (u < cnt) {
            hh[u] = (float)H[(size_t)sv[u] * HF + col];
            ds[u] = DV[sv[u]];
        }
        #pragma unroll
        for (int u = 0; u < PCH; ++u) if (u < cnt) {
            if (tv[u] == N) atomicAdd(&VR[col], ds[u] * dvN * hh[u]);
            else atomicAdd(&lsum[pv[u].x][col], ds[u] * __int_as_float(pv[u].y) * hh[u]);
        }
    }

    __syncthreads();
    float* P = partial + ((size_t)(D * NSL + slice) << 14);
    #pragma unroll 1
    for (int g = sub; g < 128; g += 2) P[g * HF + col] = lsum[g][col];
}

// pooled[dir][g][t] = sum over NSL slices of partial
__global__ __launch_bounds__(256) void k_preduce(const float* __restrict__ partial,
                                                 float* __restrict__ pooled) {
    int idx = blockIdx.x * blockDim.x + threadIdx.x;   // [0, 2*16384)
    int d = idx >> 14;
    int gt = idx & 16383;
    const float* p = partial + ((size_t)(d * NSL) << 14) + gt;
    float s = 0.f;
    #pragma unroll 8
    for (int sl = 0; sl < NSL; ++sl) s += p[(size_t)sl << 14];
    pooled[idx] = s;
}

// Per graph: z = pooled_pre + vrow_pre; u = z @ W2 + (cnt+1)*b2 per branch;
// out = relu([u_bu, u_td] @ w1 + b1) @ w2 + b2
__global__ __launch_bounds__(256) void k_mlp(
    const float* __restrict__ pooled, const float* __restrict__ vrow, const int* __restrict__ roots,
    const float* __restrict__ td_w2, const float* __restrict__ td_b2,
    const float* __restrict__ bu_w2, const float* __restrict__ bu_b2,
    const float* __restrict__ w1, const float* __restrict__ b1,
    const float* __restrict__ w2, const float* __restrict__ b2,
    float* __restrict__ out, int B)
{
    __shared__ float zsh[256];
    __shared__ float invec[256];
    __shared__ float hid[256];
    int g = blockIdx.x;
    int t = threadIdx.x;
    const float* pp_td = pooled;
    const float* pp_bu = pooled + (size_t)B * HF;
    const float* vr_td = vrow;
    const float* vr_bu = vrow + HF;
    zsh[t] = (t < 128) ? (pp_bu[g * HF + t] + vr_bu[t])
                       : (pp_td[g * HF + (t - 128)] + vr_td[t - 128]);
    __syncthreads();
    float cnt1 = (float)(roots[g + 1] - roots[g] + 1);
    float acc2;
    if (t < 128) {
        acc2 = cnt1 * bu_b2[t];
        #pragma unroll 8
        for (int k = 0; k < 128; ++k) acc2 = fmaf(zsh[k], bu_w2[k * HF + t], acc2);
    } else {
        int tt = t - 128;
        acc2 = cnt1 * td_b2[tt];
        #pragma unroll 8
        for (int k = 0; k < 128; ++k) acc2 = fmaf(zsh[128 + k], td_w2[k * HF + tt], acc2);
    }
    invec[t] = acc2;
    __syncthreads();
    float acc = b1[t];
    #pragma unroll 8
    for (int k = 0; k < 256; ++k) acc = fmaf(invec[k], w1[k * 256 + t], acc);
    hid[t] = acc > 0.f ? acc : 0.f;
    __syncthreads();
    if (t < 128) {
        float o = b2[t];
        #pragma unroll 8
        for (int k = 0; k < 256; ++k) o = fmaf(hid[k], w2[k * 128 + t], o);
        out[g * 128 + t] = o;
    }
}

extern "C" void kernel_launch(void* const* d_in, const int* in_sizes, int n_in,
                              void* d_out, int out_size, void* d_ws, size_t ws_size,
                              hipStream_t stream) {
    const float* x     = (const float*)d_in[0];
    const float* emb_w = (const float*)d_in[1];
    const float* td_w1 = (const float*)d_in[2];
    const float* td_b1 = (const float*)d_in[3];
    const float* td_w2 = (const float*)d_in[4];
    const float* td_b2 = (const float*)d_in[5];
    const float* bu_w1 = (const float*)d_in[6];
    const float* bu_b1 = (const float*)d_in[7];
    const float* bu_w2 = (const float*)d_in[8];
    const float* bu_b2 = (const float*)d_in[9];
    const float* p_w1  = (const float*)d_in[10];
    const float* p_b1  = (const float*)d_in[11];
    const float* p_w2  = (const float*)d_in[12];
    const float* p_b2  = (const float*)d_in[13];
    const int*   ei    = (const int*)d_in[14];
    const int*   batch = (const int*)d_in[15];

    int N = in_sizes[0] / INF;
    int E = in_sizes[14] / 2;
    int B = out_size / 128;
    int nv = N + 1;
    int EB = E + B;
    const int* src = ei;
    const int* dst = ei + E;

    // ---- workspace carve-up ----
    char* wsp = (char*)d_ws;
    auto alloc = [&](size_t bytes) { char* p = wsp; wsp += (bytes + 255) & ~(size_t)255; return p; };
    // zero region: [indeg 2*nv][vrow 2*HF]
    int zwords = 2 * nv + 2 * HF;
    int*    Z      = (int*)   alloc((size_t)zwords * 4);
    int*    indeg  = Z;
    float*  vrow   = (float*)(Z + 2 * nv);
    float*  dinv   = (float*) alloc((size_t)2 * nv * 4);
    int*    off    = (int*)   alloc((size_t)2 * (nv + 1) * 4);
    int*    cursor = (int*)   alloc((size_t)2 * nv * 4);
    int*    slots  = (int*)   alloc((size_t)2 * EB * 4);
    int*    dsts   = (int*)   alloc((size_t)2 * EB * 4);
    int*    bsum   = (int*)   alloc((size_t)2 * SCAN_STRIDE * 4);
    int*    roots  = (int*)   alloc((size_t)(B + 1) * 4);
    int2*   pb     = (int2*)  alloc((size_t)2 * nv * 8);
    float*  pooled = (float*) alloc((size_t)2 * B * HF * 4);
    bf16_t* Wf     = (bf16_t*)alloc((size_t)65536 * 2);
    bf16_t* RAWS   = (bf16_t*)alloc((size_t)2 * nv * HF * 2);  // dir-major
    bf16_t* AB     = (bf16_t*)alloc((size_t)2 * nv * HF * 2);  // dir-major
    float*  partial= (float*) alloc((size_t)2 * NSL * 16384 * 4);  // 16 MB

    float* vrow_td = vrow;
    float* vrow_bu = vrow + HF;
    float* out = (float*)d_out;

    dim3 b256(256), b128(128);
    int nblk = (nv + 255) / 256;
    int ngb = (nv + NPB - 1) / NPB;
    int nvb = (nv + 63) / 64;

    k_roots<<<dim3((N + 255) / 256), b256, 0, stream>>>(batch, roots, N, B);
    k_zero<<<dim3((zwords + 255) / 256), b256, 0, stream>>>(Z, zwords);
    k_wswz2<<<dim3((65536 + 255) / 256), b256, 0, stream>>>(td_w1, bu_w1, Wf);
    k_degboth<<<dim3((EB + 255) / 256), b256, 0, stream>>>(src, dst, roots, indeg, E, B, N, nv);
    k_dinvboth<<<dim3((2 * nv + 255) / 256), b256, 0, stream>>>(indeg, dinv, 2 * nv);
    k_packpb<<<dim3((2 * nv + 255) / 256), b256, 0, stream>>>(batch, dinv, pb, nv, N);
    k_scan1<<<dim3(nblk, 2), b256, 0, stream>>>(indeg, bsum, nv);
    k_scan2<<<dim3(1, 2), dim3(512), 0, stream>>>(bsum, nblk);
    k_scan3<<<dim3(nblk, 2), b256, 0, stream>>>(indeg, bsum, off, cursor, nv, EB);
    k_fill<<<dim3((EB + 255) / 256), b256, 0, stream>>>(src, dst, roots, cursor, slots, dsts, E, B, N, nv);

    k_gemm1both<<<dim3(nvb), b256, 0, stream>>>(
        x, emb_w, Wf, Wf + 32768, dinv, dinv + nv,
        RAWS, RAWS + (size_t)nv * HF, nv, N);

    k_gather1<<<dim3(ngb, 2), b128, 0, stream>>>(
        RAWS, off, slots, dsts, dinv, td_b1, bu_b1, AB, nv, EB);

    k_pool2<<<dim3(NSL, 2), b256, 0, stream>>>(
        AB, off, slots, dsts, dinv, batch, pb, partial, vrow, nv, EB, N);

    k_preduce<<<dim3(128), b256, 0, stream>>>(partial, pooled);

    k_mlp<<<dim3(B), b256, 0, stream>>>(
        pooled, vrow, roots, td_w2, td_b2, bu_w2, bu_b2,
        p_w1, p_b1, p_w2, p_b2, out, B);
}

// Round 6
// 299.453 us; speedup vs baseline: 1.8184x; 1.8184x over previous
//
#include <hip/hip_runtime.h>

typedef __bf16 bf16_t;
typedef __bf16 bf16x8 __attribute__((ext_vector_type(8)));
typedef float f32x4 __attribute__((ext_vector_type(4)));

#define INF 256
#define HF 128
#define NPB 16
#define CH 16
#define SCAN_STRIDE 512

// ---- roots[g] = first node of graph g (batch sorted, all graphs non-empty) ----
__global__ void k_roots(const int* __restrict__ batch, int* __restrict__ roots, int N, int B) {
    int i = blockIdx.x * blockDim.x + threadIdx.x;
    if (i == 0) roots[B] = N;
    if (i < N) {
        if (i == 0) roots[batch[0]] = 0;
        else if (batch[i] != batch[i - 1]) roots[batch[i]] = i;
    }
}

__global__ void k_zero(int* __restrict__ p, int n) {
    int i = blockIdx.x * blockDim.x + threadIdx.x;
    if (i < n) p[i] = 0;
}

// two W1 matrices (256x128 f32) -> bf16 MFMA B-fragment order, 32768 each
__global__ void k_wswz2(const float* __restrict__ tw1, const float* __restrict__ bw1,
                        bf16_t* __restrict__ o) {
    int idx = blockIdx.x * blockDim.x + threadIdx.x;
    if (idx >= 65536) return;
    const float* W = (idx < 32768) ? tw1 : bw1;
    bf16_t* out = o + (idx & 32768);
    int i = idx & 32767;
    int j  = i & 7;
    int l  = (i >> 3) & 63;
    int t  = i >> 9;          // kk*8 + n
    int n  = t & 7;
    int kk = t >> 3;
    int k  = kk * 32 + ((l >> 4) << 3) + j;
    int c  = (n << 4) + (l & 15);
    out[i] = (bf16_t)W[k * HF + c];
}

// in-degree for both directions. TD: d=dst. BU: d=src. Virtual edge N->root.
__global__ void k_degboth(const int* __restrict__ src, const int* __restrict__ dst,
                          const int* __restrict__ roots, int* __restrict__ indeg,
                          int E, int B, int N, int nv) {
    int e = blockIdx.x * blockDim.x + threadIdx.x;
    if (e >= E + B) return;
    int a, b;
    if (e < E) { a = src[e]; b = dst[e]; }
    else       { a = N;      b = roots[e - E]; }
    atomicAdd(&indeg[b], 1);        // TD
    atomicAdd(&indeg[nv + a], 1);   // BU
}

__global__ void k_dinvboth(const int* __restrict__ indeg, float* __restrict__ dinv, int n2) {
    int i = blockIdx.x * blockDim.x + threadIdx.x;
    if (i < n2) dinv[i] = rsqrtf(1.0f + (float)indeg[i]);  // +1 self-loop
}

// per-256-chunk sums
__global__ __launch_bounds__(256) void k_scan1(const int* __restrict__ indeg, int* __restrict__ bsum, int nv) {
    int dir = blockIdx.y;
    __shared__ int s[256];
    int t = threadIdx.x;
    int v = blockIdx.x * 256 + t;
    s[t] = (v < nv) ? indeg[dir * nv + v] : 0;
    __syncthreads();
    for (int off = 128; off > 0; off >>= 1) {
        if (t < off) s[t] += s[t + off];
        __syncthreads();
    }
    if (t == 0) bsum[dir * SCAN_STRIDE + blockIdx.x] = s[0];
}

// exclusive scan of block sums (nblk <= 512)
__global__ __launch_bounds__(512) void k_scan2(int* __restrict__ bsum, int nblk) {
    int dir = blockIdx.y;
    int* p = bsum + dir * SCAN_STRIDE;
    __shared__ int s[512];
    int t = threadIdx.x;
    int v = (t < nblk) ? p[t] : 0;
    s[t] = v;
    __syncthreads();
    for (int off = 1; off < 512; off <<= 1) {
        int u = (t >= off) ? s[t - off] : 0;
        __syncthreads();
        s[t] += u;
        __syncthreads();
    }
    if (t < nblk) p[t] = s[t] - v;  // exclusive
}

// per-element exclusive offsets + cursor copy
__global__ __launch_bounds__(256) void k_scan3(const int* __restrict__ indeg, const int* __restrict__ bsum,
                                               int* __restrict__ off, int* __restrict__ cursor,
                                               int nv, int total) {
    int dir = blockIdx.y;
    __shared__ int s[256];
    int t = threadIdx.x;
    int v0 = blockIdx.x * 256 + t;
    int val = (v0 < nv) ? indeg[dir * nv + v0] : 0;
    s[t] = val;
    __syncthreads();
    for (int o = 1; o < 256; o <<= 1) {
        int u = (t >= o) ? s[t - o] : 0;
        __syncthreads();
        s[t] += u;
        __syncthreads();
    }
    int excl = s[t] - val + bsum[dir * SCAN_STRIDE + blockIdx.x];
    if (v0 < nv) {
        off[dir * (nv + 1) + v0] = excl;
        cursor[dir * nv + v0] = excl;
    }
    if (blockIdx.x == 0 && t == 0) off[dir * (nv + 1) + nv] = total;
}

// fill slot + owner lists for both directions
__global__ void k_fill(const int* __restrict__ src, const int* __restrict__ dst,
                       const int* __restrict__ roots, int* __restrict__ cursor,
                       int* __restrict__ slots, int* __restrict__ dsts,
                       int E, int B, int N, int nv) {
    int e = blockIdx.x * blockDim.x + threadIdx.x;
    if (e >= E + B) return;
    int EB = E + B;
    int a, b;
    if (e < E) { a = src[e]; b = dst[e]; }
    else       { a = N;      b = roots[e - E]; }
    int p = atomicAdd(&cursor[b], 1);            // TD: owner b, source a
    slots[p] = a; dsts[p] = b;
    p = atomicAdd(&cursor[nv + a], 1);           // BU: owner a, source b
    slots[EB + p] = b; dsts[EB + p] = a;
}

// Dual-direction MFMA GEMM1 reading f32 X directly:
//   rawsTD[r] = dinvTD[r]*(X W1td)[r], rawsBU[r] = dinvBU[r]*(X W1bu)[r]  (bf16)
__global__ __launch_bounds__(256) void k_gemm1both(
    const float* __restrict__ x, const float* __restrict__ emb,
    const bf16_t* __restrict__ WfTD, const bf16_t* __restrict__ WfBU,
    const float* __restrict__ dinvTD, const float* __restrict__ dinvBU,
    bf16_t* __restrict__ rawsTD, bf16_t* __restrict__ rawsBU,
    int nv, int N)
{
    int lane = threadIdx.x & 63;
    int wave = threadIdx.x >> 6;
    int rowbase = blockIdx.x * 64 + wave * 16;
    int r = rowbase + (lane & 15);
    int kseg = lane >> 4;
    const float* xr = (r < N) ? (x + (size_t)r * INF) : emb;

    bf16x8 a[8];
    #pragma unroll
    for (int h = 0; h < 2; ++h) {
        float4 f[8];
        #pragma unroll
        for (int kk = 0; kk < 4; ++kk) {
            int k0 = (h * 4 + kk) * 32 + kseg * 8;
            f[2 * kk]     = *reinterpret_cast<const float4*>(xr + k0);
            f[2 * kk + 1] = *reinterpret_cast<const float4*>(xr + k0 + 4);
        }
        #pragma unroll
        for (int kk = 0; kk < 4; ++kk) {
            bf16x8 av;
            av[0] = (__bf16)f[2 * kk].x;     av[1] = (__bf16)f[2 * kk].y;
            av[2] = (__bf16)f[2 * kk].z;     av[3] = (__bf16)f[2 * kk].w;
            av[4] = (__bf16)f[2 * kk + 1].x; av[5] = (__bf16)f[2 * kk + 1].y;
            av[6] = (__bf16)f[2 * kk + 1].z; av[7] = (__bf16)f[2 * kk + 1].w;
            a[h * 4 + kk] = av;
        }
    }

    f32x4 accT[8] = {}, accB[8] = {};
    #pragma unroll
    for (int kk = 0; kk < 8; ++kk) {
        #pragma unroll
        for (int n = 0; n < 8; ++n) {
            size_t wi = (size_t)((((kk << 3) + n) << 6) + lane) * 8;
            bf16x8 bt = *reinterpret_cast<const bf16x8*>(WfTD + wi);
            accT[n] = __builtin_amdgcn_mfma_f32_16x16x32_bf16(a[kk], bt, accT[n], 0, 0, 0);
            bf16x8 bb = *reinterpret_cast<const bf16x8*>(WfBU + wi);
            accB[n] = __builtin_amdgcn_mfma_f32_16x16x32_bf16(a[kk], bb, accB[n], 0, 0, 0);
        }
    }

    int ccol = lane & 15;
    int cg = lane >> 4;
    #pragma unroll
    for (int i = 0; i < 4; ++i) {
        int rr = rowbase + cg * 4 + i;
        if (rr >= nv) continue;
        float diT = dinvTD[rr], diB = dinvBU[rr];
        bf16_t* oT = rawsTD + (size_t)rr * HF + ccol;
        bf16_t* oB = rawsBU + (size_t)rr * HF + ccol;
        #pragma unroll
        for (int n = 0; n < 8; ++n) {
            oT[n * 16] = (bf16_t)(accT[n][i] * diT);
            oB[n * 16] = (bf16_t)(accB[n][i] * diB);
        }
    }
}

// layer-1 gather, both dirs:
//   S[v] = dinv[v] * relu(dinv[v]*(raws[v] + sum_in raws[s]) + b1)   (bf16)
// (the extra dinv[v] pre-folds layer-2's source normalization)
__global__ __launch_bounds__(128) void k_gather1(
    const bf16_t* __restrict__ raws, const int* __restrict__ off,
    const int* __restrict__ slots, const int* __restrict__ dsts,
    const float* __restrict__ dinv,
    const float* __restrict__ td_b1, const float* __restrict__ bu_b1,
    bf16_t* __restrict__ ab, int nv, int EB)
{
    int dir = blockIdx.y;
    const bf16_t* R  = raws + (size_t)dir * nv * HF;
    const int*    OF = off + (size_t)dir * (nv + 1);
    const int*    SL = slots + (size_t)dir * EB;
    const int*    DS = dsts + (size_t)dir * EB;
    const float*  DV = dinv + (size_t)dir * nv;
    const float*  bias = dir ? bu_b1 : td_b1;
    bf16_t* AB = ab + (size_t)dir * nv * HF;

    __shared__ float lsum[NPB][HF];
    int t = threadIdx.x;
    int v0 = blockIdx.x * NPB;
    int nloc = min(NPB, nv - v0);

    #pragma unroll 1
    for (int j = 0; j < nloc; ++j)
        lsum[j][t] = (float)R[(size_t)(v0 + j) * HF + t];

    int e0 = OF[v0], e1 = OF[v0 + nloc];
    #pragma unroll 1
    for (int i = e0; i < e1; i += CH) {
        int cnt = min(CH, e1 - i);
        int sl[CH], dd[CH]; float vals[CH];
        #pragma unroll
        for (int u = 0; u < CH; ++u) if (u < cnt) { sl[u] = SL[i + u]; dd[u] = DS[i + u]; }
        #pragma unroll
        for (int u = 0; u < CH; ++u) if (u < cnt) vals[u] = (float)R[(size_t)sl[u] * HF + t];
        #pragma unroll
        for (int u = 0; u < CH; ++u) if (u < cnt) lsum[dd[u] - v0][t] += vals[u];
    }

    float bs = bias[t];
    #pragma unroll 1
    for (int j = 0; j < nloc; ++j) {
        int v = v0 + j;
        float dv = DV[v];
        float val = dv * lsum[j][t] + bs;
        AB[(size_t)v * HF + t] = (bf16_t)(dv * fmaxf(val, 0.f));
    }
}

// layer-2 gather + pool, both dirs:
//   G[v] = dinv[v]*(S[v] + sum_in S[s]);  pooled[g] += G[v] (run-length); vrow = G[N]
__global__ __launch_bounds__(128) void k_gather2pool(
    const bf16_t* __restrict__ ab, const int* __restrict__ off,
    const int* __restrict__ slots, const int* __restrict__ dsts,
    const float* __restrict__ dinv, const int* __restrict__ batch,
    float* __restrict__ pooled, float* __restrict__ vrow,
    int nv, int EB, int N, int B)
{
    int dir = blockIdx.y;
    const bf16_t* S  = ab + (size_t)dir * nv * HF;
    const int*    OF = off + (size_t)dir * (nv + 1);
    const int*    SL = slots + (size_t)dir * EB;
    const int*    DS = dsts + (size_t)dir * EB;
    const float*  DV = dinv + (size_t)dir * nv;
    float* PP = pooled + (size_t)dir * B * HF;
    float* VR = vrow + dir * HF;

    __shared__ float lsum[NPB][HF];
    int t = threadIdx.x;
    int v0 = blockIdx.x * NPB;
    int nloc = min(NPB, nv - v0);

    #pragma unroll 1
    for (int j = 0; j < nloc; ++j)
        lsum[j][t] = (float)S[(size_t)(v0 + j) * HF + t];

    int e0 = OF[v0], e1 = OF[v0 + nloc];
    #pragma unroll 1
    for (int i = e0; i < e1; i += CH) {
        int cnt = min(CH, e1 - i);
        int sl[CH], dd[CH]; float vals[CH];
        #pragma unroll
        for (int u = 0; u < CH; ++u) if (u < cnt) { sl[u] = SL[i + u]; dd[u] = DS[i + u]; }
        #pragma unroll
        for (int u = 0; u < CH; ++u) if (u < cnt) vals[u] = (float)S[(size_t)sl[u] * HF + t];
        #pragma unroll
        for (int u = 0; u < CH; ++u) if (u < cnt) lsum[dd[u] - v0][t] += vals[u];
    }

    // run-length pooling over sorted batch; vrow written directly (node N in one block)
    float accum = 0.f;
    int curg = -1;
    #pragma unroll 1
    for (int j = 0; j < nloc; ++j) {
        int v = v0 + j;
        float G = DV[v] * lsum[j][t];
        if (v == N) { VR[t] = G; continue; }
        int g = batch[v];
        if (g != curg) {
            if (curg >= 0) atomicAdd(&PP[curg * HF + t], accum);
            curg = g; accum = 0.f;
        }
        accum += G;
    }
    if (curg >= 0) atomicAdd(&PP[curg * HF + t], accum);
}

// Per graph: z = pooled_pre + vrow_pre; u = z @ W2 + (cnt+1)*b2 per branch;
// out = relu([u_bu, u_td] @ w1 + b1) @ w2 + b2
__global__ __launch_bounds__(256) void k_mlp(
    const float* __restrict__ pooled, const float* __restrict__ vrow, const int* __restrict__ roots,
    const float* __restrict__ td_w2, const float* __restrict__ td_b2,
    const float* __restrict__ bu_w2, const float* __restrict__ bu_b2,
    const float* __restrict__ w1, const float* __restrict__ b1,
    const float* __restrict__ w2, const float* __restrict__ b2,
    float* __restrict__ out, int B)
{
    __shared__ float zsh[256];
    __shared__ float invec[256];
    __shared__ float hid[256];
    int g = blockIdx.x;
    int t = threadIdx.x;
    const float* pp_td = pooled;
    const float* pp_bu = pooled + (size_t)B * HF;
    const float* vr_td = vrow;
    const float* vr_bu = vrow + HF;
    zsh[t] = (t < 128) ? (pp_bu[g * HF + t] + vr_bu[t])
                       : (pp_td[g * HF + (t - 128)] + vr_td[t - 128]);
    __syncthreads();
    float cnt1 = (float)(roots[g + 1] - roots[g] + 1);
    float acc2;
    if (t < 128) {
        acc2 = cnt1 * bu_b2[t];
        #pragma unroll 8
        for (int k = 0; k < 128; ++k) acc2 = fmaf(zsh[k], bu_w2[k * HF + t], acc2);
    } else {
        int tt = t - 128;
        acc2 = cnt1 * td_b2[tt];
        #pragma unroll 8
        for (int k = 0; k < 128; ++k) acc2 = fmaf(zsh[128 + k], td_w2[k * HF + tt], acc2);
    }
    invec[t] = acc2;
    __syncthreads();
    float acc = b1[t];
    #pragma unroll 8
    for (int k = 0; k < 256; ++k) acc = fmaf(invec[k], w1[k * 256 + t], acc);
    hid[t] = acc > 0.f ? acc : 0.f;
    __syncthreads();
    if (t < 128) {
        float o = b2[t];
        #pragma unroll 8
        for (int k = 0; k < 256; ++k) o = fmaf(hid[k], w2[k * 128 + t], o);
        out[g * 128 + t] = o;
    }
}

extern "C" void kernel_launch(void* const* d_in, const int* in_sizes, int n_in,
                              void* d_out, int out_size, void* d_ws, size_t ws_size,
                              hipStream_t stream) {
    const float* x     = (const float*)d_in[0];
    const float* emb_w = (const float*)d_in[1];
    const float* td_w1 = (const float*)d_in[2];
    const float* td_b1 = (const float*)d_in[3];
    const float* td_w2 = (const float*)d_in[4];
    const float* td_b2 = (const float*)d_in[5];
    const float* bu_w1 = (const float*)d_in[6];
    const float* bu_b1 = (const float*)d_in[7];
    const float* bu_w2 = (const float*)d_in[8];
    const float* bu_b2 = (const float*)d_in[9];
    const float* p_w1  = (const float*)d_in[10];
    const float* p_b1  = (const float*)d_in[11];
    const float* p_w2  = (const float*)d_in[12];
    const float* p_b2  = (const float*)d_in[13];
    const int*   ei    = (const int*)d_in[14];
    const int*   batch = (const int*)d_in[15];

    int N = in_sizes[0] / INF;
    int E = in_sizes[14] / 2;
    int B = out_size / 128;
    int nv = N + 1;
    int EB = E + B;
    const int* src = ei;
    const int* dst = ei + E;

    // ---- workspace carve-up ----
    char* wsp = (char*)d_ws;
    auto alloc = [&](size_t bytes) { char* p = wsp; wsp += (bytes + 255) & ~(size_t)255; return p; };
    // zero region: [indeg 2*nv][pooled 2*B*HF][vrow 2*HF]
    int zwords = 2 * nv + 2 * B * HF + 2 * HF;
    int*    Z      = (int*)   alloc((size_t)zwords * 4);
    int*    indeg  = Z;
    float*  pooled = (float*)(Z + 2 * nv);
    float*  vrow   = pooled + 2 * B * HF;
    float*  dinv   = (float*) alloc((size_t)2 * nv * 4);
    int*    off    = (int*)   alloc((size_t)2 * (nv + 1) * 4);
    int*    cursor = (int*)   alloc((size_t)2 * nv * 4);
    int*    slots  = (int*)   alloc((size_t)2 * EB * 4);
    int*    dsts   = (int*)   alloc((size_t)2 * EB * 4);
    int*    bsum   = (int*)   alloc((size_t)2 * SCAN_STRIDE * 4);
    int*    roots  = (int*)   alloc((size_t)(B + 1) * 4);
    bf16_t* Wf     = (bf16_t*)alloc((size_t)65536 * 2);
    bf16_t* RAWS   = (bf16_t*)alloc((size_t)2 * nv * HF * 2);  // dir-major
    bf16_t* AB     = (bf16_t*)alloc((size_t)2 * nv * HF * 2);  // dir-major

    float* out = (float*)d_out;

    dim3 b256(256), b128(128);
    int nblk = (nv + 255) / 256;
    int ngb = (nv + NPB - 1) / NPB;
    int nvb = (nv + 63) / 64;

    k_roots<<<dim3((N + 255) / 256), b256, 0, stream>>>(batch, roots, N, B);
    k_zero<<<dim3((zwords + 255) / 256), b256, 0, stream>>>(Z, zwords);
    k_wswz2<<<dim3((65536 + 255) / 256), b256, 0, stream>>>(td_w1, bu_w1, Wf);
    k_degboth<<<dim3((EB + 255) / 256), b256, 0, stream>>>(src, dst, roots, indeg, E, B, N, nv);
    k_dinvboth<<<dim3((2 * nv + 255) / 256), b256, 0, stream>>>(indeg, dinv, 2 * nv);
    k_scan1<<<dim3(nblk, 2), b256, 0, stream>>>(indeg, bsum, nv);
    k_scan2<<<dim3(1, 2), dim3(512), 0, stream>>>(bsum, nblk);
    k_scan3<<<dim3(nblk, 2), b256, 0, stream>>>(indeg, bsum, off, cursor, nv, EB);
    k_fill<<<dim3((EB + 255) / 256), b256, 0, stream>>>(src, dst, roots, cursor, slots, dsts, E, B, N, nv);

    k_gemm1both<<<dim3(nvb), b256, 0, stream>>>(
        x, emb_w, Wf, Wf + 32768, dinv, dinv + nv,
        RAWS, RAWS + (size_t)nv * HF, nv, N);

    k_gather1<<<dim3(ngb, 2), b128, 0, stream>>>(
        RAWS, off, slots, dsts, dinv, td_b1, bu_b1, AB, nv, EB);

    k_gather2pool<<<dim3(ngb, 2), b128, 0, stream>>>(
        AB, off, slots, dsts, dinv, batch, pooled, vrow, nv, EB, N, B);

    k_mlp<<<dim3(B), b256, 0, stream>>>(
        pooled, vrow, roots, td_w2, td_b2, bu_w2, bu_b2,
        p_w1, p_b1, p_w2, p_b2, out, B);
}

// Round 7
// 283.543 us; speedup vs baseline: 1.9204x; 1.0561x over previous
//
#include <hip/hip_runtime.h>

typedef __bf16 bf16_t;
typedef __bf16 bf16x8 __attribute__((ext_vector_type(8)));
typedef float f32x4 __attribute__((ext_vector_type(4)));

#define INF 256
#define HF 128
#define NPB 16
#define CH 16
#define SCAN_STRIDE 512

// ---- roots[g] = first node of graph g (batch sorted, all graphs non-empty) ----
__global__ void k_roots(const int* __restrict__ batch, int* __restrict__ roots, int N, int B) {
    int i = blockIdx.x * blockDim.x + threadIdx.x;
    if (i == 0) roots[B] = N;
    if (i < N) {
        if (i == 0) roots[batch[0]] = 0;
        else if (batch[i] != batch[i - 1]) roots[batch[i]] = i;
    }
}

__global__ void k_zero(int* __restrict__ p, int n) {
    int i = blockIdx.x * blockDim.x + threadIdx.x;
    if (i < n) p[i] = 0;
}

// two W1 matrices (256x128 f32) -> bf16 MFMA B-fragment order, 32768 each
__global__ void k_wswz2(const float* __restrict__ tw1, const float* __restrict__ bw1,
                        bf16_t* __restrict__ o) {
    int idx = blockIdx.x * blockDim.x + threadIdx.x;
    if (idx >= 65536) return;
    const float* W = (idx < 32768) ? tw1 : bw1;
    bf16_t* out = o + (idx & 32768);
    int i = idx & 32767;
    int j  = i & 7;
    int l  = (i >> 3) & 63;
    int t  = i >> 9;          // kk*8 + n
    int n  = t & 7;
    int kk = t >> 3;
    int k  = kk * 32 + ((l >> 4) << 3) + j;
    int c  = (n << 4) + (l & 15);
    out[i] = (bf16_t)W[k * HF + c];
}

// in-degree for both directions. TD: d=dst. BU: d=src. Virtual edge N->root.
__global__ void k_degboth(const int* __restrict__ src, const int* __restrict__ dst,
                          const int* __restrict__ roots, int* __restrict__ indeg,
                          int E, int B, int N, int nv) {
    int e = blockIdx.x * blockDim.x + threadIdx.x;
    if (e >= E + B) return;
    int a, b;
    if (e < E) { a = src[e]; b = dst[e]; }
    else       { a = N;      b = roots[e - E]; }
    atomicAdd(&indeg[b], 1);        // TD
    atomicAdd(&indeg[nv + a], 1);   // BU
}

__global__ void k_dinvboth(const int* __restrict__ indeg, float* __restrict__ dinv, int n2) {
    int i = blockIdx.x * blockDim.x + threadIdx.x;
    if (i < n2) dinv[i] = rsqrtf(1.0f + (float)indeg[i]);  // +1 self-loop
}

// per-256-chunk sums
__global__ __launch_bounds__(256) void k_scan1(const int* __restrict__ indeg, int* __restrict__ bsum, int nv) {
    int dir = blockIdx.y;
    __shared__ int s[256];
    int t = threadIdx.x;
    int v = blockIdx.x * 256 + t;
    s[t] = (v < nv) ? indeg[dir * nv + v] : 0;
    __syncthreads();
    for (int off = 128; off > 0; off >>= 1) {
        if (t < off) s[t] += s[t + off];
        __syncthreads();
    }
    if (t == 0) bsum[dir * SCAN_STRIDE + blockIdx.x] = s[0];
}

// exclusive scan of block sums (nblk <= 512)
__global__ __launch_bounds__(512) void k_scan2(int* __restrict__ bsum, int nblk) {
    int dir = blockIdx.y;
    int* p = bsum + dir * SCAN_STRIDE;
    __shared__ int s[512];
    int t = threadIdx.x;
    int v = (t < nblk) ? p[t] : 0;
    s[t] = v;
    __syncthreads();
    for (int off = 1; off < 512; off <<= 1) {
        int u = (t >= off) ? s[t - off] : 0;
        __syncthreads();
        s[t] += u;
        __syncthreads();
    }
    if (t < nblk) p[t] = s[t] - v;  // exclusive
}

// per-element exclusive offsets + cursor copy
__global__ __launch_bounds__(256) void k_scan3(const int* __restrict__ indeg, const int* __restrict__ bsum,
                                               int* __restrict__ off, int* __restrict__ cursor,
                                               int nv, int total) {
    int dir = blockIdx.y;
    __shared__ int s[256];
    int t = threadIdx.x;
    int v0 = blockIdx.x * 256 + t;
    int val = (v0 < nv) ? indeg[dir * nv + v0] : 0;
    s[t] = val;
    __syncthreads();
    for (int o = 1; o < 256; o <<= 1) {
        int u = (t >= o) ? s[t - o] : 0;
        __syncthreads();
        s[t] += u;
        __syncthreads();
    }
    int excl = s[t] - val + bsum[dir * SCAN_STRIDE + blockIdx.x];
    if (v0 < nv) {
        off[dir * (nv + 1) + v0] = excl;
        cursor[dir * nv + v0] = excl;
    }
    if (blockIdx.x == 0 && t == 0) off[dir * (nv + 1) + nv] = total;
}

// fill slot + owner lists for both directions
__global__ void k_fill(const int* __restrict__ src, const int* __restrict__ dst,
                       const int* __restrict__ roots, int* __restrict__ cursor,
                       int* __restrict__ slots, int* __restrict__ dsts,
                       int E, int B, int N, int nv) {
    int e = blockIdx.x * blockDim.x + threadIdx.x;
    if (e >= E + B) return;
    int EB = E + B;
    int a, b;
    if (e < E) { a = src[e]; b = dst[e]; }
    else       { a = N;      b = roots[e - E]; }
    int p = atomicAdd(&cursor[b], 1);            // TD: owner b, source a
    slots[p] = a; dsts[p] = b;
    p = atomicAdd(&cursor[nv + a], 1);           // BU: owner a, source b
    slots[EB + p] = b; dsts[EB + p] = a;
}

// Dual-direction MFMA GEMM1 reading f32 X directly:
//   rawsTD[r] = dinvTD[r]*(X W1td)[r], rawsBU[r] = dinvBU[r]*(X W1bu)[r]  (bf16)
__global__ __launch_bounds__(256) void k_gemm1both(
    const float* __restrict__ x, const float* __restrict__ emb,
    const bf16_t* __restrict__ WfTD, const bf16_t* __restrict__ WfBU,
    const float* __restrict__ dinvTD, const float* __restrict__ dinvBU,
    bf16_t* __restrict__ rawsTD, bf16_t* __restrict__ rawsBU,
    int nv, int N)
{
    int lane = threadIdx.x & 63;
    int wave = threadIdx.x >> 6;
    int rowbase = blockIdx.x * 64 + wave * 16;
    int r = rowbase + (lane & 15);
    int kseg = lane >> 4;
    const float* xr = (r < N) ? (x + (size_t)r * INF) : emb;

    bf16x8 a[8];
    #pragma unroll
    for (int h = 0; h < 2; ++h) {
        float4 f[8];
        #pragma unroll
        for (int kk = 0; kk < 4; ++kk) {
            int k0 = (h * 4 + kk) * 32 + kseg * 8;
            f[2 * kk]     = *reinterpret_cast<const float4*>(xr + k0);
            f[2 * kk + 1] = *reinterpret_cast<const float4*>(xr + k0 + 4);
        }
        #pragma unroll
        for (int kk = 0; kk < 4; ++kk) {
            bf16x8 av;
            av[0] = (__bf16)f[2 * kk].x;     av[1] = (__bf16)f[2 * kk].y;
            av[2] = (__bf16)f[2 * kk].z;     av[3] = (__bf16)f[2 * kk].w;
            av[4] = (__bf16)f[2 * kk + 1].x; av[5] = (__bf16)f[2 * kk + 1].y;
            av[6] = (__bf16)f[2 * kk + 1].z; av[7] = (__bf16)f[2 * kk + 1].w;
            a[h * 4 + kk] = av;
        }
    }

    f32x4 accT[8] = {}, accB[8] = {};
    #pragma unroll
    for (int kk = 0; kk < 8; ++kk) {
        #pragma unroll
        for (int n = 0; n < 8; ++n) {
            size_t wi = (size_t)((((kk << 3) + n) << 6) + lane) * 8;
            bf16x8 bt = *reinterpret_cast<const bf16x8*>(WfTD + wi);
            accT[n] = __builtin_amdgcn_mfma_f32_16x16x32_bf16(a[kk], bt, accT[n], 0, 0, 0);
            bf16x8 bb = *reinterpret_cast<const bf16x8*>(WfBU + wi);
            accB[n] = __builtin_amdgcn_mfma_f32_16x16x32_bf16(a[kk], bb, accB[n], 0, 0, 0);
        }
    }

    int ccol = lane & 15;
    int cg = lane >> 4;
    #pragma unroll
    for (int i = 0; i < 4; ++i) {
        int rr = rowbase + cg * 4 + i;
        if (rr >= nv) continue;
        float diT = dinvTD[rr], diB = dinvBU[rr];
        bf16_t* oT = rawsTD + (size_t)rr * HF + ccol;
        bf16_t* oB = rawsBU + (size_t)rr * HF + ccol;
        #pragma unroll
        for (int n = 0; n < 8; ++n) {
            oT[n * 16] = (bf16_t)(accT[n][i] * diT);
            oB[n * 16] = (bf16_t)(accB[n][i] * diB);
        }
    }
}

// layer-1 gather, both dirs:
//   S[v] = dinv[v] * relu(dinv[v]*(raws[v] + sum_in raws[s]) + b1)   (bf16)
// Load batches are fenced with sched_barrier(0) so all CH row-loads are
// truly in flight before the LDS accumulate consumes them.
__global__ __launch_bounds__(128) void k_gather1(
    const bf16_t* __restrict__ raws, const int* __restrict__ off,
    const int* __restrict__ slots, const int* __restrict__ dsts,
    const float* __restrict__ dinv,
    const float* __restrict__ td_b1, const float* __restrict__ bu_b1,
    bf16_t* __restrict__ ab, int nv, int EB)
{
    int dir = blockIdx.y;
    const bf16_t* R  = raws + (size_t)dir * nv * HF;
    const int*    OF = off + (size_t)dir * (nv + 1);
    const int*    SL = slots + (size_t)dir * EB;
    const int*    DS = dsts + (size_t)dir * EB;
    const float*  DV = dinv + (size_t)dir * nv;
    const float*  bias = dir ? bu_b1 : td_b1;
    bf16_t* AB = ab + (size_t)dir * nv * HF;

    __shared__ float lsum[NPB][HF];
    int t = threadIdx.x;
    int v0 = blockIdx.x * NPB;
    int nloc = min(NPB, nv - v0);

    // batched self-term loads (16 independent loads in flight)
    float selfv[NPB];
    #pragma unroll
    for (int j = 0; j < NPB; ++j) {
        int v = min(v0 + j, nv - 1);
        selfv[j] = (float)R[(size_t)v * HF + t];
    }
    __builtin_amdgcn_sched_barrier(0);
    #pragma unroll
    for (int j = 0; j < NPB; ++j) lsum[j][t] = selfv[j];

    int e0 = OF[v0], e1 = OF[min(v0 + NPB, nv)];
    #pragma unroll 1
    for (int i = e0; i < e1; i += CH) {
        int cnt = min(CH, e1 - i);
        int sl[CH], dd[CH];
        #pragma unroll
        for (int u = 0; u < CH; ++u) if (u < cnt) { sl[u] = SL[i + u]; dd[u] = DS[i + u]; }
        __builtin_amdgcn_sched_barrier(0);
        float vals[CH];
        #pragma unroll
        for (int u = 0; u < CH; ++u) if (u < cnt) vals[u] = (float)R[(size_t)sl[u] * HF + t];
        __builtin_amdgcn_sched_barrier(0);
        #pragma unroll
        for (int u = 0; u < CH; ++u) if (u < cnt) lsum[dd[u] - v0][t] += vals[u];
    }

    float bs = bias[t];
    #pragma unroll 1
    for (int j = 0; j < nloc; ++j) {
        int v = v0 + j;
        float dv = DV[v];
        float val = dv * lsum[j][t] + bs;
        AB[(size_t)v * HF + t] = (bf16_t)(dv * fmaxf(val, 0.f));
    }
}

// layer-2 gather + pool, both dirs:
//   G[v] = dinv[v]*(S[v] + sum_in S[s]);  pooled[g] += G[v] (run-length); vrow = G[N]
__global__ __launch_bounds__(128) void k_gather2pool(
    const bf16_t* __restrict__ ab, const int* __restrict__ off,
    const int* __restrict__ slots, const int* __restrict__ dsts,
    const float* __restrict__ dinv, const int* __restrict__ batch,
    float* __restrict__ pooled, float* __restrict__ vrow,
    int nv, int EB, int N, int B)
{
    int dir = blockIdx.y;
    const bf16_t* S  = ab + (size_t)dir * nv * HF;
    const int*    OF = off + (size_t)dir * (nv + 1);
    const int*    SL = slots + (size_t)dir * EB;
    const int*    DS = dsts + (size_t)dir * EB;
    const float*  DV = dinv + (size_t)dir * nv;
    float* PP = pooled + (size_t)dir * B * HF;
    float* VR = vrow + dir * HF;

    __shared__ float lsum[NPB][HF];
    int t = threadIdx.x;
    int v0 = blockIdx.x * NPB;
    int nloc = min(NPB, nv - v0);

    float selfv[NPB];
    #pragma unroll
    for (int j = 0; j < NPB; ++j) {
        int v = min(v0 + j, nv - 1);
        selfv[j] = (float)S[(size_t)v * HF + t];
    }
    __builtin_amdgcn_sched_barrier(0);
    #pragma unroll
    for (int j = 0; j < NPB; ++j) lsum[j][t] = selfv[j];

    int e0 = OF[v0], e1 = OF[min(v0 + NPB, nv)];
    #pragma unroll 1
    for (int i = e0; i < e1; i += CH) {
        int cnt = min(CH, e1 - i);
        int sl[CH], dd[CH];
        #pragma unroll
        for (int u = 0; u < CH; ++u) if (u < cnt) { sl[u] = SL[i + u]; dd[u] = DS[i + u]; }
        __builtin_amdgcn_sched_barrier(0);
        float vals[CH];
        #pragma unroll
        for (int u = 0; u < CH; ++u) if (u < cnt) vals[u] = (float)S[(size_t)sl[u] * HF + t];
        __builtin_amdgcn_sched_barrier(0);
        #pragma unroll
        for (int u = 0; u < CH; ++u) if (u < cnt) lsum[dd[u] - v0][t] += vals[u];
    }

    // run-length pooling over sorted batch; vrow written directly (node N in one block)
    float accum = 0.f;
    int curg = -1;
    #pragma unroll 1
    for (int j = 0; j < nloc; ++j) {
        int v = v0 + j;
        float G = DV[v] * lsum[j][t];
        if (v == N) { VR[t] = G; continue; }
        int g = batch[v];
        if (g != curg) {
            if (curg >= 0) atomicAdd(&PP[curg * HF + t], accum);
            curg = g; accum = 0.f;
        }
        accum += G;
    }
    if (curg >= 0) atomicAdd(&PP[curg * HF + t], accum);
}

// Per graph: z = pooled_pre + vrow_pre; u = z @ W2 + (cnt+1)*b2 per branch;
// out = relu([u_bu, u_td] @ w1 + b1) @ w2 + b2
__global__ __launch_bounds__(256) void k_mlp(
    const float* __restrict__ pooled, const float* __restrict__ vrow, const int* __restrict__ roots,
    const float* __restrict__ td_w2, const float* __restrict__ td_b2,
    const float* __restrict__ bu_w2, const float* __restrict__ bu_b2,
    const float* __restrict__ w1, const float* __restrict__ b1,
    const float* __restrict__ w2, const float* __restrict__ b2,
    float* __restrict__ out, int B)
{
    __shared__ float zsh[256];
    __shared__ float invec[256];
    __shared__ float hid[256];
    int g = blockIdx.x;
    int t = threadIdx.x;
    const float* pp_td = pooled;
    const float* pp_bu = pooled + (size_t)B * HF;
    const float* vr_td = vrow;
    const float* vr_bu = vrow + HF;
    zsh[t] = (t < 128) ? (pp_bu[g * HF + t] + vr_bu[t])
                       : (pp_td[g * HF + (t - 128)] + vr_td[t - 128]);
    __syncthreads();
    float cnt1 = (float)(roots[g + 1] - roots[g] + 1);
    float acc2;
    if (t < 128) {
        acc2 = cnt1 * bu_b2[t];
        #pragma unroll 8
        for (int k = 0; k < 128; ++k) acc2 = fmaf(zsh[k], bu_w2[k * HF + t], acc2);
    } else {
        int tt = t - 128;
        acc2 = cnt1 * td_b2[tt];
        #pragma unroll 8
        for (int k = 0; k < 128; ++k) acc2 = fmaf(zsh[128 + k], td_w2[k * HF + tt], acc2);
    }
    invec[t] = acc2;
    __syncthreads();
    float acc = b1[t];
    #pragma unroll 8
    for (int k = 0; k < 256; ++k) acc = fmaf(invec[k], w1[k * 256 + t], acc);
    hid[t] = acc > 0.f ? acc : 0.f;
    __syncthreads();
    if (t < 128) {
        float o = b2[t];
        #pragma unroll 8
        for (int k = 0; k < 256; ++k) o = fmaf(hid[k], w2[k * 128 + t], o);
        out[g * 128 + t] = o;
    }
}

extern "C" void kernel_launch(void* const* d_in, const int* in_sizes, int n_in,
                              void* d_out, int out_size, void* d_ws, size_t ws_size,
                              hipStream_t stream) {
    const float* x     = (const float*)d_in[0];
    const float* emb_w = (const float*)d_in[1];
    const float* td_w1 = (const float*)d_in[2];
    const float* td_b1 = (const float*)d_in[3];
    const float* td_w2 = (const float*)d_in[4];
    const float* td_b2 = (const float*)d_in[5];
    const float* bu_w1 = (const float*)d_in[6];
    const float* bu_b1 = (const float*)d_in[7];
    const float* bu_w2 = (const float*)d_in[8];
    const float* bu_b2 = (const float*)d_in[9];
    const float* p_w1  = (const float*)d_in[10];
    const float* p_b1  = (const float*)d_in[11];
    const float* p_w2  = (const float*)d_in[12];
    const float* p_b2  = (const float*)d_in[13];
    const int*   ei    = (const int*)d_in[14];
    const int*   batch = (const int*)d_in[15];

    int N = in_sizes[0] / INF;
    int E = in_sizes[14] / 2;
    int B = out_size / 128;
    int nv = N + 1;
    int EB = E + B;
    const int* src = ei;
    const int* dst = ei + E;

    // ---- workspace carve-up ----
    char* wsp = (char*)d_ws;
    auto alloc = [&](size_t bytes) { char* p = wsp; wsp += (bytes + 255) & ~(size_t)255; return p; };
    // zero region: [indeg 2*nv][pooled 2*B*HF][vrow 2*HF]
    int zwords = 2 * nv + 2 * B * HF + 2 * HF;
    int*    Z      = (int*)   alloc((size_t)zwords * 4);
    int*    indeg  = Z;
    float*  pooled = (float*)(Z + 2 * nv);
    float*  vrow   = pooled + 2 * B * HF;
    float*  dinv   = (float*) alloc((size_t)2 * nv * 4);
    int*    off    = (int*)   alloc((size_t)2 * (nv + 1) * 4);
    int*    cursor = (int*)   alloc((size_t)2 * nv * 4);
    int*    slots  = (int*)   alloc((size_t)2 * EB * 4);
    int*    dsts   = (int*)   alloc((size_t)2 * EB * 4);
    int*    bsum   = (int*)   alloc((size_t)2 * SCAN_STRIDE * 4);
    int*    roots  = (int*)   alloc((size_t)(B + 1) * 4);
    bf16_t* Wf     = (bf16_t*)alloc((size_t)65536 * 2);
    bf16_t* RAWS   = (bf16_t*)alloc((size_t)2 * nv * HF * 2);  // dir-major
    bf16_t* AB     = (bf16_t*)alloc((size_t)2 * nv * HF * 2);  // dir-major

    float* out = (float*)d_out;

    dim3 b256(256), b128(128);
    int nblk = (nv + 255) / 256;
    int ngb = (nv + NPB - 1) / NPB;
    int nvb = (nv + 63) / 64;

    k_roots<<<dim3((N + 255) / 256), b256, 0, stream>>>(batch, roots, N, B);
    k_zero<<<dim3((zwords + 255) / 256), b256, 0, stream>>>(Z, zwords);
    k_wswz2<<<dim3((65536 + 255) / 256), b256, 0, stream>>>(td_w1, bu_w1, Wf);
    k_degboth<<<dim3((EB + 255) / 256), b256, 0, stream>>>(src, dst, roots, indeg, E, B, N, nv);
    k_dinvboth<<<dim3((2 * nv + 255) / 256), b256, 0, stream>>>(indeg, dinv, 2 * nv);
    k_scan1<<<dim3(nblk, 2), b256, 0, stream>>>(indeg, bsum, nv);
    k_scan2<<<dim3(1, 2), dim3(512), 0, stream>>>(bsum, nblk);
    k_scan3<<<dim3(nblk, 2), b256, 0, stream>>>(indeg, bsum, off, cursor, nv, EB);
    k_fill<<<dim3((EB + 255) / 256), b256, 0, stream>>>(src, dst, roots, cursor, slots, dsts, E, B, N, nv);

    k_gemm1both<<<dim3(nvb), b256, 0, stream>>>(
        x, emb_w, Wf, Wf + 32768, dinv, dinv + nv,
        RAWS, RAWS + (size_t)nv * HF, nv, N);

    k_gather1<<<dim3(ngb, 2), b128, 0, stream>>>(
        RAWS, off, slots, dsts, dinv, td_b1, bu_b1, AB, nv, EB);

    k_gather2pool<<<dim3(ngb, 2), b128, 0, stream>>>(
        AB, off, slots, dsts, dinv, batch, pooled, vrow, nv, EB, N, B);

    k_mlp<<<dim3(B), b256, 0, stream>>>(
        pooled, vrow, roots, td_w2, td_b2, bu_w2, bu_b2,
        p_w1, p_b1, p_w2, p_b2, out, B);
}